// Round 1
// baseline (256.613 us; speedup 1.0000x reference)
//
#include <hip/hip_runtime.h>

// LSTM: B=32768, T=28, D=28, H=8, gates=32, classes=10.
//
// Re-mapped vs previous version: 32 lanes per batch element, lane l5=(tid&31)
// owns ONE gate column l5 of W (layout [36][32], col order i|j|f|o, so
// column index == lane index). Per-lane W footprint = 36 VGPRs (vs 144
// before, which the register allocator could not hold -> it rematerialized
// ~144 global W loads per timestep; VGPR_Count=116 proved Wr never lived in
// registers). Now W is genuinely register-resident: ZERO in-loop W traffic.
//
// A 32-lane element group == one wave64 half, so all cross-lane exchange is
// ds_swizzle (BitMode, per-32-lane-half, compile-time offset, no addr VGPR):
//   - gather i,j,f,o activations for the c-update: 4 swizzles
//   - broadcast the 8 h values for the next step's h-FMAs: 8 swizzles
//
// Gate nonlinearity made lane-uniform (no divergence) via per-lane consts:
//   a = qK + mK * rcp(1 + exp2(sK * z))
//   gt!=1 (i,f,o): sK=-log2(e), mK=1,  qK=0  -> sigmoid(z)
//   gt==1 (j):     sK=2*log2(e), mK=-2, qK=1 -> tanh(z)
//   forget bias folded into the preloaded bias (gt==2 adds 1.0).
//
// 4096 blocks x 256 threads = 16384 waves (4/SIMD resident at <=128 VGPR).

#define TSTEPS 28
#define DIN    28
#define NH     8
#define NG     32   // 4*NH
#define NC     10
#define NROWS  36   // DIN + NH

__device__ __forceinline__ float fexp2(float x) { return __builtin_amdgcn_exp2f(x); }
__device__ __forceinline__ float frcp(float x)  { return __builtin_amdgcn_rcpf(x); }

// BitMode ds_swizzle: src_lane = ((lane & and) | or) ^ xor, per 32-lane half.
// offset = (xor<<10) | (or<<5) | and
#define SWZ(v, imm) \
    __int_as_float(__builtin_amdgcn_ds_swizzle(__float_as_int(v), (imm)))

__global__ __launch_bounds__(256, 4) void lstm_kernel(
    const float* __restrict__ x,      // [B, T, D]
    const float* __restrict__ W,      // [36, 32]  col order i,j,f,o
    const float* __restrict__ bias,   // [32]
    const float* __restrict__ Wout,   // [8, 10]
    const float* __restrict__ bout,   // [10]
    float* __restrict__ out)          // [B, 10]
{
    const int tid = blockIdx.x * 256 + threadIdx.x;
    const int e   = tid >> 5;             // batch element (32 lanes each)
    const int l5  = threadIdx.x & 31;     // gate column owned by this lane
    const int gt  = l5 >> 3;              // gate type 0..3 = i,j,f,o

    const float* xb = x + (size_t)e * (TSTEPS * DIN);

    // This lane's single gate column of W: 36 VGPRs. Coalesced 128B loads
    // across the wave (both halves read the same line -> broadcast).
    float Wr[NROWS];
#pragma unroll
    for (int k = 0; k < NROWS; ++k) Wr[k] = W[k * NG + l5];

    // Per-lane activation constants (kill gate-type divergence).
    const float bg = bias[l5] + (gt == 2 ? 1.0f : 0.0f);     // forget bias
    const float sK = (gt == 1) ?  2.8853900817779268f : -1.4426950408889634f;
    const float mK = (gt == 1) ? -2.0f : 1.0f;
    const float qK = (gt == 1) ?  1.0f : 0.0f;

    float c = 0.0f;
    float hall[NH];
#pragma unroll
    for (int j = 0; j < NH; ++j) hall[j] = 0.0f;

    // Prefetch x_0 (28 floats = 7 float4); all 32 lanes of the group read
    // identical addresses -> single broadcast transaction each.
    float4 xq[7];
    {
        const float4* xv = (const float4*)xb;
#pragma unroll
        for (int i = 0; i < 7; ++i) xq[i] = xv[i];
    }

#pragma unroll 1
    for (int t = 0; t < TSTEPS; ++t) {
        float xt[DIN];
#pragma unroll
        for (int i = 0; i < 7; ++i) {
            xt[4*i+0] = xq[i].x; xt[4*i+1] = xq[i].y;
            xt[4*i+2] = xq[i].z; xt[4*i+3] = xq[i].w;
        }
        if (t + 1 < TSTEPS) {
            const float4* xv = (const float4*)(xb + (t + 1) * DIN);
#pragma unroll
            for (int i = 0; i < 7; ++i) xq[i] = xv[i];
        }

        // One gate pre-activation: 28 x-FMAs + 8 h-FMAs, all-register.
        float g = bg;
#pragma unroll
        for (int k = 0; k < DIN; ++k)
            g = fmaf(xt[k], Wr[k], g);
#pragma unroll
        for (int k = 0; k < NH; ++k)
            g = fmaf(hall[k], Wr[DIN + k], g);

        // Uniform activation: sigmoid (i,f,o) or tanh (j) via constants.
        float a = fmaf(mK, frcp(1.0f + fexp2(sK * g)), qK);

        // Gather the four activated gates of this lane's unit u = l5&7.
        // src = (lane & 7) | (gate*8):  and=0x07, or=gate<<3.
        float iv = SWZ(a, 0x0007);
        float jv = SWZ(a, 0x0107);
        float fv = SWZ(a, 0x0207);
        float ov = SWZ(a, 0x0307);

        // Cell update (replicated across the unit's 4 gate-lanes).
        c = fmaf(c, fv, iv * jv);
        float th = fmaf(-2.0f, frcp(1.0f + fexp2(2.8853900817779268f * c)), 1.0f);
        float hu = th * ov;

        // Broadcast h of units 0..7 (lane j of each half holds unit j's h).
        // src = j: and=0x00, or=j.
        hall[0] = SWZ(hu, 0x0000);
        hall[1] = SWZ(hu, 0x0020);
        hall[2] = SWZ(hu, 0x0040);
        hall[3] = SWZ(hu, 0x0060);
        hall[4] = SWZ(hu, 0x0080);
        hall[5] = SWZ(hu, 0x00A0);
        hall[6] = SWZ(hu, 0x00C0);
        hall[7] = SWZ(hu, 0x00E0);
    }

    // logits = h @ Wout + bout; lanes 0..9 of each group write one column.
    if (l5 < NC) {
        float acc = bout[l5];
#pragma unroll
        for (int k = 0; k < NH; ++k)
            acc = fmaf(hall[k], Wout[k * NC + l5], acc);
        out[(size_t)e * NC + l5] = acc;
    }
}

extern "C" void kernel_launch(void* const* d_in, const int* in_sizes, int n_in,
                              void* d_out, int out_size, void* d_ws, size_t ws_size,
                              hipStream_t stream) {
    const float* x    = (const float*)d_in[0];
    const float* W    = (const float*)d_in[1];
    const float* b    = (const float*)d_in[2];
    const float* Wout = (const float*)d_in[3];
    const float* bout = (const float*)d_in[4];
    float* out = (float*)d_out;

    const int B = in_sizes[0] / (TSTEPS * DIN);  // 32768
    const int threads = B * NG;                  // 32 lanes per element
    const int block = 256;
    const int grid = threads / block;            // 4096
    lstm_kernel<<<grid, block, 0, stream>>>(x, W, b, Wout, bout, out);
}

// Round 2
// 254.420 us; speedup vs baseline: 1.0086x; 1.0086x over previous
//
#include <hip/hip_runtime.h>

// LSTM: B=32768, T=28, D=28, H=8, gates=32, classes=10.
//
// Mapping: 32 lanes per batch element; lane l5=(tid&31) owns ONE gate column
// l5 of W (layout [36][32], col order i|j|f|o -> column index == lane index).
// Per-lane W footprint = 36 VGPRs.
//
// Round-1 lesson (VGPR_Count=56, WRITE_SIZE=output-only): the compiler SANK
// the 36 W preload loads into the t-loop instead of keeping them resident —
// ~36 cache-hit global loads per lane per timestep on the critical path.
// Fix: pin each Wr[k] with an empty `asm volatile("" : "+v")` after the
// preload. The asm result is neither rematerializable nor sinkable, so the
// allocator must keep all 36 values in VGPRs across the loop.
// Budget: 36 W + 2x28 x ping/pong + 8 h + ~15 misc ~= 115 < 128 cap
// (__launch_bounds__(256,4)) -> no spill expected.
//
// Round-1 lesson #2: single-accumulator g had a 36-FMA dependent chain
// (~144 cyc/step of pure latency). Now 4 partial accumulators (9-deep
// chains) + 2-level add tree: ~44 cyc.
//
// Cross-lane exchange via BitMode ds_swizzle (compile-time imm, per
// 32-lane half): 4 gathers (i,j,f,o) + 8 broadcasts (h) per step.
// Gate nonlinearity is lane-uniform via per-lane constants:
//   a = qK + mK * rcp(1 + exp2(sK * z))
//   i,f,o: sK=-log2(e), mK=1,  qK=0  -> sigmoid(z)
//   j:     sK=2*log2(e), mK=-2, qK=1 -> tanh(z)
//   forget bias (+1) folded into the preloaded bias for gt==2.

#define TSTEPS 28
#define DIN    28
#define NH     8
#define NG     32   // 4*NH
#define NC     10
#define NROWS  36   // DIN + NH

__device__ __forceinline__ float fexp2(float x) { return __builtin_amdgcn_exp2f(x); }
__device__ __forceinline__ float frcp(float x)  { return __builtin_amdgcn_rcpf(x); }

// BitMode ds_swizzle: src_lane = ((lane & and) | or) ^ xor, per 32-lane half.
// offset = (xor<<10) | (or<<5) | and
#define SWZ(v, imm) \
    __int_as_float(__builtin_amdgcn_ds_swizzle(__float_as_int(v), (imm)))

__global__ __launch_bounds__(256, 4) void lstm_kernel(
    const float* __restrict__ x,      // [B, T, D]
    const float* __restrict__ W,      // [36, 32]  col order i,j,f,o
    const float* __restrict__ bias,   // [32]
    const float* __restrict__ Wout,   // [8, 10]
    const float* __restrict__ bout,   // [10]
    float* __restrict__ out)          // [B, 10]
{
    const int tid = blockIdx.x * 256 + threadIdx.x;
    const int e   = tid >> 5;             // batch element (32 lanes each)
    const int l5  = threadIdx.x & 31;     // gate column owned by this lane
    const int gt  = l5 >> 3;              // gate type 0..3 = i,j,f,o

    const float* xb = x + (size_t)e * (TSTEPS * DIN);

    // Preload this lane's gate column of W (36 values), then PIN them in
    // VGPRs so the allocator cannot sink the loads into the loop.
    float Wr[NROWS];
#pragma unroll
    for (int k = 0; k < NROWS; ++k) Wr[k] = W[k * NG + l5];
#pragma unroll
    for (int k = 0; k < NROWS; ++k) asm volatile("" : "+v"(Wr[k]));

    // Per-lane activation constants (kill gate-type divergence).
    const float bg = bias[l5] + (gt == 2 ? 1.0f : 0.0f);     // forget bias
    const float sK = (gt == 1) ?  2.8853900817779268f : -1.4426950408889634f;
    const float mK = (gt == 1) ? -2.0f : 1.0f;
    const float qK = (gt == 1) ?  1.0f : 0.0f;

    float c = 0.0f;
    float hall[NH];
#pragma unroll
    for (int j = 0; j < NH; ++j) hall[j] = 0.0f;

    // Prefetch x_0 (28 floats = 7 float4); all 32 lanes of the group read
    // identical addresses -> broadcast-coalesced.
    float4 xq[7];
    {
        const float4* xv = (const float4*)xb;
#pragma unroll
        for (int i = 0; i < 7; ++i) xq[i] = xv[i];
    }

#pragma unroll 1
    for (int t = 0; t < TSTEPS; ++t) {
        float xt[DIN];
#pragma unroll
        for (int i = 0; i < 7; ++i) {
            xt[4*i+0] = xq[i].x; xt[4*i+1] = xq[i].y;
            xt[4*i+2] = xq[i].z; xt[4*i+3] = xq[i].w;
        }
        if (t + 1 < TSTEPS) {
            const float4* xn = (const float4*)(xb + (t + 1) * DIN);
#pragma unroll
            for (int i = 0; i < 7; ++i) xq[i] = xn[i];
        }

        // Gate pre-activation: 28 x-FMAs + 8 h-FMAs, 4 independent chains.
        float g0 = bg, g1 = 0.0f, g2 = 0.0f, g3 = 0.0f;
#pragma unroll
        for (int k = 0; k < DIN; k += 4) {
            g0 = fmaf(xt[k+0], Wr[k+0], g0);
            g1 = fmaf(xt[k+1], Wr[k+1], g1);
            g2 = fmaf(xt[k+2], Wr[k+2], g2);
            g3 = fmaf(xt[k+3], Wr[k+3], g3);
        }
#pragma unroll
        for (int k = 0; k < NH; k += 4) {
            g0 = fmaf(hall[k+0], Wr[DIN+k+0], g0);
            g1 = fmaf(hall[k+1], Wr[DIN+k+1], g1);
            g2 = fmaf(hall[k+2], Wr[DIN+k+2], g2);
            g3 = fmaf(hall[k+3], Wr[DIN+k+3], g3);
        }
        float g = (g0 + g1) + (g2 + g3);

        // Uniform activation: sigmoid (i,f,o) or tanh (j) via constants.
        float a = fmaf(mK, frcp(1.0f + fexp2(sK * g)), qK);

        // Gather the four activated gates of this lane's unit u = l5&7.
        // src = (lane & 7) | (gate*8):  and=0x07, or=gate<<3.
        float iv = SWZ(a, 0x0007);
        float jv = SWZ(a, 0x0107);
        float fv = SWZ(a, 0x0207);
        float ov = SWZ(a, 0x0307);

        // Cell update (replicated across the unit's 4 gate-lanes).
        c = fmaf(c, fv, iv * jv);
        float th = fmaf(-2.0f, frcp(1.0f + fexp2(2.8853900817779268f * c)), 1.0f);
        float hu = th * ov;

        // Broadcast h of units 0..7 (lane j of each half holds unit j's h).
        // src = j: and=0x00, or=j.
        hall[0] = SWZ(hu, 0x0000);
        hall[1] = SWZ(hu, 0x0020);
        hall[2] = SWZ(hu, 0x0040);
        hall[3] = SWZ(hu, 0x0060);
        hall[4] = SWZ(hu, 0x0080);
        hall[5] = SWZ(hu, 0x00A0);
        hall[6] = SWZ(hu, 0x00C0);
        hall[7] = SWZ(hu, 0x00E0);
    }

    // logits = h @ Wout + bout; lanes 0..9 of each group write one column.
    if (l5 < NC) {
        float acc = bout[l5];
#pragma unroll
        for (int k = 0; k < NH; ++k)
            acc = fmaf(hall[k], Wout[k * NC + l5], acc);
        out[(size_t)e * NC + l5] = acc;
    }
}

extern "C" void kernel_launch(void* const* d_in, const int* in_sizes, int n_in,
                              void* d_out, int out_size, void* d_ws, size_t ws_size,
                              hipStream_t stream) {
    const float* x    = (const float*)d_in[0];
    const float* W    = (const float*)d_in[1];
    const float* b    = (const float*)d_in[2];
    const float* Wout = (const float*)d_in[3];
    const float* bout = (const float*)d_in[4];
    float* out = (float*)d_out;

    const int B = in_sizes[0] / (TSTEPS * DIN);  // 32768
    const int threads = B * NG;                  // 32 lanes per element
    const int block = 256;
    const int grid = threads / block;            // 4096
    lstm_kernel<<<grid, block, 0, stream>>>(x, W, b, Wout, bout, out);
}